// Round 2
// baseline (22703.421 us; speedup 1.0000x reference)
//
#include <hip/hip_runtime.h>
#include <stdint.h>
#include <math.h>

// CipherRNN: B=64, S=1024, V=128, E=512, H=512, L=2, O=256
#define B_ 64
#define S_ 1024
#define V_ 128
#define E_ 512
#define H_ 512
#define O_ 256

#define G_  4      // batch groups of 16 rows
#define CB_ 4      // column blocks of 128 cols
#define D0_ 4      // h0 ring depth
#define DX_ 8      // X1 ring depth
#define D1_ 4      // h1 ring depth

typedef __attribute__((ext_vector_type(8))) short bf16x8;
typedef __attribute__((ext_vector_type(4))) float f32x4;
typedef unsigned short u16;
typedef unsigned int u32;

__device__ __forceinline__ u16 f2bf(float f) {
  unsigned u = __builtin_bit_cast(unsigned, f);
  u = u + 0x7FFFu + ((u >> 16) & 1u);   // RNE
  return (u16)(u >> 16);
}
__device__ __forceinline__ float bf2f(u16 h) {
  unsigned u = ((unsigned)h) << 16;
  return __builtin_bit_cast(float, u);
}

__device__ __forceinline__ void wait_ge(u32* p, u32 tgt) {
  while (__hip_atomic_load(p, __ATOMIC_ACQUIRE, __HIP_MEMORY_SCOPE_AGENT) < tgt)
    __builtin_amdgcn_s_sleep(2);
}
__device__ __forceinline__ void post(u32* p) {
  __hip_atomic_fetch_add(p, 1u, __ATOMIC_RELEASE, __HIP_MEMORY_SCOPE_AGENT);
}

// Load B-fragments of W (row-major [n][k]) for one 16-col tile as hi/lo bf16.
// Lane holds col n, k = ks*32 + lhi*8 + j.
__device__ __forceinline__ void load_wfrags(const float* __restrict__ W, int n, int lhi,
                                            bf16x8* whi, bf16x8* wlo) {
  const float* wr = W + (size_t)n * H_ + lhi * 8;
  #pragma unroll
  for (int ks = 0; ks < 16; ++ks) {
    const float* src = wr + ks * 32;
    bf16x8 h, l;
    #pragma unroll
    for (int j = 0; j < 8; ++j) {
      const float v = src[j];
      const u16 hb = f2bf(v);
      h[j] = (short)hb;
      l[j] = (short)f2bf(v - bf2f(hb));
    }
    whi[ks] = h; wlo[ks] = l;
  }
}

// Emulated-fp32 GEMM tile: acc += A*W with A,W split hi/lo (3 MFMAs, skip lo*lo).
__device__ __forceinline__ f32x4 mm3(const u16* __restrict__ Ahi, const u16* __restrict__ Alo,
                                     const bf16x8* whi, const bf16x8* wlo, f32x4 acc) {
  #pragma unroll
  for (int ks = 0; ks < 16; ++ks) {
    const bf16x8 ah = *(const bf16x8*)(Ahi + ks * 32);
    const bf16x8 al = *(const bf16x8*)(Alo + ks * 32);
    acc = __builtin_amdgcn_mfma_f32_16x16x32_bf16(ah, whi[ks], acc, 0, 0, 0);
    acc = __builtin_amdgcn_mfma_f32_16x16x32_bf16(al, whi[ks], acc, 0, 0, 0);
    acc = __builtin_amdgcn_mfma_f32_16x16x32_bf16(ah, wlo[ks], acc, 0, 0, 0);
  }
  return acc;
}

// ---------------------------------------------------------------------------
// EW0[v][n] = sum_e emb[v][e]*Wxh0[n][e] + bh0[n]   (f32 exact, V=128)
// ---------------------------------------------------------------------------
__global__ void k_embed(const float* __restrict__ emb, const float* __restrict__ Wxh0,
                        const float* __restrict__ bh0, float* __restrict__ EW0) {
  __shared__ float es[E_];
  const int v = blockIdx.x;
  for (int e = threadIdx.x; e < E_; e += blockDim.x) es[e] = emb[v * E_ + e];
  __syncthreads();
  for (int h = threadIdx.x; h < H_; h += blockDim.x) {
    const float* wr = Wxh0 + (size_t)h * E_;
    float acc = bh0[h];
    #pragma unroll 4
    for (int e = 0; e < E_; e += 4)
      acc += es[e] * wr[e] + es[e+1] * wr[e+1] + es[e+2] * wr[e+2] + es[e+3] * wr[e+3];
    EW0[(size_t)v * H_ + h] = acc;
  }
}

// ---------------------------------------------------------------------------
// Persistent 3-stage pipeline: role 0 = rnn layer0, role 1 = X1 GEMM,
// role 2 = rnn layer1. 48 blocks = 3 roles x 4 groups x 4 col-blocks.
// Each block: 512 thr (8 waves x 16 cols), weights hi/lo resident in VGPRs.
// ---------------------------------------------------------------------------
__global__ __launch_bounds__(512, 2) void k_pipe(
    const float* __restrict__ Whh,   // [2][512][512]
    const float* __restrict__ Wxh,   // [2][512][512]
    const int* __restrict__ ids,     // [B][S]
    const float* __restrict__ EW0,   // [V][H] f32
    const float* __restrict__ bh,    // [2][512]
    u16* __restrict__ h0hi_r, u16* __restrict__ h0lo_r,   // [D0][64][512]
    float* __restrict__ x1_r,                              // [DX][64][512]
    u16* __restrict__ h1hi_r, u16* __restrict__ h1lo_r,   // [D1][64][512]
    u16* __restrict__ h1full,                              // [B*S][512]
    u32* f0, u32* fx, u32* f1)                             // [4][S] counters
{
  const int tid  = threadIdx.x;
  const int wave = tid >> 6, lane = tid & 63;
  const int l15 = lane & 15, lhi = lane >> 4;
  const int bid = blockIdx.x;
  const int role = bid >> 4, sub = bid & 15;
  const int g = sub >> 2, cb = sub & 3;
  const int n = cb * 128 + wave * 16 + l15;   // this lane's output column
  const int arow = g * 16 + l15;              // A-frag row (batch)
  const int koff = lhi * 8;
  const size_t SLOT = (size_t)B_ * H_;

  const float* Wsel = (role == 0) ? Whh
                    : (role == 1) ? (Wxh + (size_t)H_ * H_)
                                  : (Whh + (size_t)H_ * H_);
  bf16x8 whi[16], wlo[16];
  load_wfrags(Wsel, n, lhi, whi, wlo);

  if (role == 0) {                    // ---- layer-0 recurrence ----
    for (int t = 0; t < S_; ++t) {
      if (tid == 0) {
        if (t >= 1)   wait_ge(&f0[g * S_ + t - 1], 4);
        if (t >= D0_) wait_ge(&fx[g * S_ + t - D0_], 4);   // ring backpressure
      }
      __syncthreads();
      f32x4 acc = {0.f, 0.f, 0.f, 0.f};
      if (t > 0) {
        const size_t rb = (size_t)((t - 1) % D0_) * SLOT + (size_t)arow * H_ + koff;
        acc = mm3(h0hi_r + rb, h0lo_r + rb, whi, wlo, acc);
      }
      const size_t wbase = (size_t)(t % D0_) * SLOT;
      #pragma unroll
      for (int j = 0; j < 4; ++j) {
        const int b = g * 16 + lhi * 4 + j;
        const float pre = acc[j] + EW0[(size_t)ids[b * S_ + t] * H_ + n];
        const float h = tanhf(pre);
        const u16 hb = f2bf(h);
        h0hi_r[wbase + b * H_ + n] = hb;
        h0lo_r[wbase + b * H_ + n] = f2bf(h - bf2f(hb));
      }
      __threadfence();
      __syncthreads();
      if (tid == 0) post(&f0[g * S_ + t]);
    }
  } else if (role == 1) {             // ---- X1 = h0 @ Wxh1^T + bh1 (f32) ----
    const float bias = bh[H_ + n];
    for (int t = 0; t < S_; ++t) {
      if (tid == 0) {
        wait_ge(&f0[g * S_ + t], 4);
        if (t >= DX_) wait_ge(&f1[g * S_ + t - DX_], 4);   // ring backpressure
      }
      __syncthreads();
      const size_t rb = (size_t)(t % D0_) * SLOT + (size_t)arow * H_ + koff;
      f32x4 acc = {0.f, 0.f, 0.f, 0.f};
      acc = mm3(h0hi_r + rb, h0lo_r + rb, whi, wlo, acc);
      float* xo = x1_r + (size_t)(t % DX_) * SLOT;
      #pragma unroll
      for (int j = 0; j < 4; ++j) {
        const int b = g * 16 + lhi * 4 + j;
        xo[b * H_ + n] = acc[j] + bias;
      }
      __threadfence();
      __syncthreads();
      if (tid == 0) post(&fx[g * S_ + t]);
    }
  } else {                            // ---- layer-1 recurrence ----
    for (int t = 0; t < S_; ++t) {
      if (tid == 0) {
        wait_ge(&fx[g * S_ + t], 4);
        if (t >= 1) wait_ge(&f1[g * S_ + t - 1], 4);
      }
      __syncthreads();
      f32x4 acc = {0.f, 0.f, 0.f, 0.f};
      if (t > 0) {
        const size_t rb = (size_t)((t - 1) % D1_) * SLOT + (size_t)arow * H_ + koff;
        acc = mm3(h1hi_r + rb, h1lo_r + rb, whi, wlo, acc);
      }
      const float* xi = x1_r + (size_t)(t % DX_) * SLOT;
      const size_t wbase = (size_t)(t % D1_) * SLOT;
      #pragma unroll
      for (int j = 0; j < 4; ++j) {
        const int b = g * 16 + lhi * 4 + j;
        const float pre = acc[j] + xi[b * H_ + n];
        const float h = tanhf(pre);
        const u16 hb = f2bf(h);
        h1hi_r[wbase + b * H_ + n] = hb;
        h1lo_r[wbase + b * H_ + n] = f2bf(h - bf2f(hb));
        h1full[((size_t)b * S_ + t) * H_ + n] = hb;
      }
      __threadfence();
      __syncthreads();
      if (tid == 0) post(&f1[g * S_ + t]);
    }
  }
}

// ---------------------------------------------------------------------------
// out[m][o] = sum_k h1[m][k]*Why[o][k] + by[o]   (f32 out; single-pass bf16,
// error ~1e-3, not amplified)
// ---------------------------------------------------------------------------
__global__ void k_gemm_out(const u16* __restrict__ A, const float* __restrict__ Bw,
                           const float* __restrict__ bias, float* __restrict__ outp) {
  const int tid  = threadIdx.x;
  const int wave = tid >> 6, lane = tid & 63;
  const int l15 = lane & 15, lhi = lane >> 4;
  const int m0  = blockIdx.x * 16;
  const int ncb = wave * 64;

  const u16* arow = A + ((size_t)(m0 + l15)) * H_ + lhi * 8;
  bf16x8 afr[16];
  #pragma unroll
  for (int ks = 0; ks < 16; ++ks) afr[ks] = *(const bf16x8*)(arow + ks * 32);

  f32x4 acc[4];
  #pragma unroll
  for (int nt = 0; nt < 4; ++nt) {
    const int nn = ncb + nt * 16 + l15;
    const float* wr = Bw + (size_t)nn * H_ + lhi * 8;
    f32x4 z = {0.f, 0.f, 0.f, 0.f};
    acc[nt] = z;
    #pragma unroll
    for (int ks = 0; ks < 16; ++ks) {
      const float* src = wr + ks * 32;
      bf16x8 w;
      #pragma unroll
      for (int j = 0; j < 8; ++j) w[j] = (short)f2bf(src[j]);
      acc[nt] = __builtin_amdgcn_mfma_f32_16x16x32_bf16(afr[ks], w, acc[nt], 0, 0, 0);
    }
  }
  #pragma unroll
  for (int nt = 0; nt < 4; ++nt) {
    const int nn = ncb + nt * 16 + l15;
    const float bs = bias[nn];
    #pragma unroll
    for (int j = 0; j < 4; ++j)
      outp[(size_t)(m0 + lhi * 4 + j) * O_ + nn] = acc[nt][j] + bs;
  }
}

// ---------------------------------------------------------------------------
extern "C" void kernel_launch(void* const* d_in, const int* in_sizes, int n_in,
                              void* d_out, int out_size, void* d_ws, size_t ws_size,
                              hipStream_t stream) {
  const int*   ids = (const int*)d_in[0];
  const float* emb = (const float*)d_in[1];
  const float* Wxh = (const float*)d_in[2];
  const float* Whh = (const float*)d_in[3];
  const float* bh  = (const float*)d_in[4];
  const float* Why = (const float*)d_in[5];
  const float* by  = (const float*)d_in[6];
  float* out = (float*)d_out;

  char* ws = (char*)d_ws;
  size_t off = 0;
  float* EW0    = (float*)(ws + off); off += (size_t)V_ * H_ * 4;           // 256 KB
  u16* h0hi_r   = (u16*)(ws + off);   off += (size_t)D0_ * B_ * H_ * 2;     // 256 KB
  u16* h0lo_r   = (u16*)(ws + off);   off += (size_t)D0_ * B_ * H_ * 2;     // 256 KB
  float* x1_r   = (float*)(ws + off); off += (size_t)DX_ * B_ * H_ * 4;     // 1 MB
  u16* h1hi_r   = (u16*)(ws + off);   off += (size_t)D1_ * B_ * H_ * 2;     // 256 KB
  u16* h1lo_r   = (u16*)(ws + off);   off += (size_t)D1_ * B_ * H_ * 2;     // 256 KB
  u16* h1full   = (u16*)(ws + off);   off += (size_t)B_ * S_ * H_ * 2;      // 67 MB
  u32* f0       = (u32*)(ws + off);   off += (size_t)G_ * S_ * 4;           // 16 KB
  u32* fx       = (u32*)(ws + off);   off += (size_t)G_ * S_ * 4;           // 16 KB
  u32* f1       = (u32*)(ws + off);   off += (size_t)G_ * S_ * 4;           // 16 KB

  // flags must start at zero every call
  hipMemsetAsync(f0, 0, (size_t)3 * G_ * S_ * 4, stream);

  k_embed<<<dim3(V_), dim3(256), 0, stream>>>(emb, Wxh, bh, EW0);

  k_pipe<<<dim3(48), dim3(512), 0, stream>>>(Whh, Wxh, ids, EW0, bh,
                                             h0hi_r, h0lo_r, x1_r,
                                             h1hi_r, h1lo_r, h1full,
                                             f0, fx, f1);

  k_gemm_out<<<dim3((B_ * S_) / 16), dim3(256), 0, stream>>>(h1full, Why, by, out);
}

// Round 3
// 5173.491 us; speedup vs baseline: 4.3884x; 4.3884x over previous
//
#include <hip/hip_runtime.h>
#include <stdint.h>
#include <math.h>

// CipherRNN: B=64, S=1024, V=128, E=512, H=512, L=2, O=256
#define B_ 64
#define S_ 1024
#define V_ 128
#define E_ 512
#define H_ 512
#define O_ 256

#define D0_ 16          // h0 ring depth
#define DX_ 16          // x1 ring depth
#define D1_ 4           // h1 ring depth
#define SLOTU (B_ * H_) // 32768 elements per ring slot

typedef __attribute__((ext_vector_type(8))) short bf16x8;
typedef __attribute__((ext_vector_type(4))) float f32x4;
typedef __attribute__((ext_vector_type(4))) unsigned int u32x4;
typedef unsigned short u16;
typedef unsigned int u32;

__device__ __forceinline__ u16 f2bf(float f) {
  unsigned u = __builtin_bit_cast(unsigned, f);
  u = u + 0x7FFFu + ((u >> 16) & 1u);   // RNE
  return (u16)(u >> 16);
}
__device__ __forceinline__ float bf2f(u16 h) {
  unsigned u = ((unsigned)h) << 16;
  return __builtin_bit_cast(float, u);
}

// ---- L3-coherent (bypass L1+L2, no cache-maintenance) communication ops ----
__device__ __forceinline__ u32x4 ld_sc1_x4(const u32* p) {
  u32x4 v;
  asm volatile("global_load_dwordx4 %0, %1, off sc0 sc1" : "=v"(v) : "v"(p));
  return v;
}
__device__ __forceinline__ float ld_sc1_f32(const float* p) {
  float v;
  asm volatile("global_load_dword %0, %1, off sc0 sc1" : "=v"(v) : "v"(p));
  return v;
}
__device__ __forceinline__ void st_sc1_u32(u32* p, u32 v) {
  asm volatile("global_store_dword %0, %1, off sc0 sc1" :: "v"(p), "v"(v) : "memory");
}
__device__ __forceinline__ void poll_ge(const u32* p, u32 tgt) {
  for (;;) {
    u32 v;
    asm volatile("global_load_dword %0, %1, off sc0 sc1\n\ts_waitcnt vmcnt(0)"
                 : "=v"(v) : "v"(p) : "memory");
    if (v >= tgt) return;
    __builtin_amdgcn_s_sleep(1);
  }
}
__device__ __forceinline__ void post_sc1(u32* p) {
  u32 one = 1u;
  asm volatile("s_waitcnt vmcnt(0)\n\tglobal_atomic_add %0, %1, off sc1"
               :: "v"(p), "v"(one) : "memory");
}
__device__ __forceinline__ void vm0_fence() {
  asm volatile("s_waitcnt vmcnt(0)" ::: "memory");
  __builtin_amdgcn_sched_barrier(0);
}

__device__ __forceinline__ u32 pk_hi(u32 a, u32 b) { return (a & 0xffffu) | (b << 16); }
__device__ __forceinline__ u32 pk_lo(u32 a, u32 b) { return (a >> 16) | (b & 0xffff0000u); }

// ---------------------------------------------------------------------------
// EW0[v][n] = sum_e emb[v][e]*Wxh0[n][e] + bh0[n]   (f32 exact, V=128)
// ---------------------------------------------------------------------------
__global__ void k_embed(const float* __restrict__ emb, const float* __restrict__ Wxh0,
                        const float* __restrict__ bh0, float* __restrict__ EW0) {
  __shared__ float es[E_];
  const int v = blockIdx.x;
  for (int e = threadIdx.x; e < E_; e += blockDim.x) es[e] = emb[v * E_ + e];
  __syncthreads();
  for (int h = threadIdx.x; h < H_; h += blockDim.x) {
    const float* wr = Wxh0 + (size_t)h * E_;
    float acc = bh0[h];
    #pragma unroll 4
    for (int e = 0; e < E_; e += 4)
      acc += es[e] * wr[e] + es[e+1] * wr[e+1] + es[e+2] * wr[e+2] + es[e+3] * wr[e+3];
    EW0[(size_t)v * H_ + h] = acc;
  }
}

// ---------------------------------------------------------------------------
// Persistent 3-stage pipeline, L3-coherent flags + rings, L2 untouched.
// 48 blocks = 3 roles x 4 groups (16 batch rows) x 4 col-blocks (128 cols).
// Rings store h as packed u32 = hi | lo<<16; staged+deinterleaved into LDS.
// ---------------------------------------------------------------------------
__global__ __launch_bounds__(512, 2) void k_pipe(
    const float* __restrict__ Whh,   // [2][512][512]
    const float* __restrict__ Wxh,   // [2][512][512]
    const int* __restrict__ ids,     // [B][S]
    const float* __restrict__ EW0,   // [V][H] f32
    const float* __restrict__ bh,    // [2][512]
    u32* __restrict__ h0r,           // [D0][64][512] packed hi|lo
    float* __restrict__ x1r,         // [DX][64][512] f32
    u32* __restrict__ h1r,           // [D1][64][512] packed hi|lo
    u16* __restrict__ h1full,        // [B*S][512] bf16 (plain cached)
    u32* __restrict__ f0, u32* __restrict__ fx, u32* __restrict__ f1) // [4][S]
{
  __shared__ u32 lds_hi[16 * 256];   // 16 KB: A-tile hi, 16 rows x 512 bf16
  __shared__ u32 lds_lo[16 * 256];   // 16 KB: A-tile lo

  const int tid  = threadIdx.x;
  const int wave = tid >> 6, lane = tid & 63;
  const int l15 = lane & 15, lhi = lane >> 4;
  const int bid = blockIdx.x;
  const int role = bid >> 4, sub = bid & 15;
  const int g = sub >> 2, cb = sub & 3;
  const int n = cb * 128 + wave * 16 + l15;   // this lane's output column
  const int goff = g * 16 * H_;               // group offset inside a ring slot

  // ---- resident weights (hi/lo bf16 B-fragments), plain cached loads ----
  const float* Wsel = (role == 0) ? Whh
                    : (role == 1) ? (Wxh + (size_t)H_ * H_)
                                  : (Whh + (size_t)H_ * H_);
  bf16x8 whi[16], wlo[16];
  {
    const float* wr = Wsel + (size_t)n * H_ + lhi * 8;
    #pragma unroll
    for (int ks = 0; ks < 16; ++ks) {
      const float* src = wr + ks * 32;
      bf16x8 h, l;
      #pragma unroll
      for (int j = 0; j < 8; ++j) {
        const float v = src[j];
        const u16 hb = f2bf(v);
        h[j] = (short)hb;
        l[j] = (short)f2bf(v - bf2f(hb));
      }
      whi[ks] = h; wlo[ks] = l;
    }
  }

  // ---- precomputed swizzled LDS read offsets (A-frag: row=l15, k=ks*32+lhi*8) ----
  int aoff[16];
  {
    const int sw = l15 & 7;
    #pragma unroll
    for (int ks = 0; ks < 16; ++ks)
      aoff[ks] = l15 * 1024 + (((ks * 4 + lhi) ^ sw) << 4);
  }

  // ---- stage one 16x512 packed tile from L3 ring into LDS (deinterleave) ----
  auto stage = [&](const u32* src) {
    const int r = tid >> 5, cg = tid & 31;
    const u32* p = src + r * H_ + cg * 16;
    u32x4 q0 = ld_sc1_x4(p);
    u32x4 q1 = ld_sc1_x4(p + 4);
    u32x4 q2 = ld_sc1_x4(p + 8);
    u32x4 q3 = ld_sc1_x4(p + 12);
    vm0_fence();
    u32x4 h0v = { pk_hi(q0.x,q0.y), pk_hi(q0.z,q0.w), pk_hi(q1.x,q1.y), pk_hi(q1.z,q1.w) };
    u32x4 h1v = { pk_hi(q2.x,q2.y), pk_hi(q2.z,q2.w), pk_hi(q3.x,q3.y), pk_hi(q3.z,q3.w) };
    u32x4 l0v = { pk_lo(q0.x,q0.y), pk_lo(q0.z,q0.w), pk_lo(q1.x,q1.y), pk_lo(q1.z,q1.w) };
    u32x4 l1v = { pk_lo(q2.x,q2.y), pk_lo(q2.z,q2.w), pk_lo(q3.x,q3.y), pk_lo(q3.z,q3.w) };
    const int sw = r & 7, ch = cg * 2;
    const int rb = r * 1024;
    *(u32x4*)((char*)lds_hi + rb + (((ch    ) ^ sw) << 4)) = h0v;
    *(u32x4*)((char*)lds_hi + rb + (((ch + 1) ^ sw) << 4)) = h1v;
    *(u32x4*)((char*)lds_lo + rb + (((ch    ) ^ sw) << 4)) = l0v;
    *(u32x4*)((char*)lds_lo + rb + (((ch + 1) ^ sw) << 4)) = l1v;
  };

  // ---- emulated-fp32 matmul from LDS tile (3 independent MFMA chains) ----
  auto mm3 = [&](f32x4& out) {
    f32x4 c0 = {0.f,0.f,0.f,0.f}, c1 = c0, c2 = c0;
    #pragma unroll
    for (int ks = 0; ks < 16; ++ks) {
      bf16x8 ah = *(const bf16x8*)((const char*)lds_hi + aoff[ks]);
      bf16x8 al = *(const bf16x8*)((const char*)lds_lo + aoff[ks]);
      c0 = __builtin_amdgcn_mfma_f32_16x16x32_bf16(ah, whi[ks], c0, 0, 0, 0);
      c1 = __builtin_amdgcn_mfma_f32_16x16x32_bf16(al, whi[ks], c1, 0, 0, 0);
      c2 = __builtin_amdgcn_mfma_f32_16x16x32_bf16(ah, wlo[ks], c2, 0, 0, 0);
    }
    out = c0 + c1 + c2;
  };

  if (role == 0) {                    // ======== layer-0 recurrence ========
    for (int t = 0; t < S_; ++t) {
      // prefetchable, flag-independent loads (plain cached; L2-resident)
      float ew[4];
      #pragma unroll
      for (int j = 0; j < 4; ++j) {
        const int b = g * 16 + lhi * 4 + j;
        ew[j] = EW0[(size_t)ids[b * S_ + t] * H_ + n];
      }
      if ((t & 7) == 0 && t >= D0_) poll_ge(&fx[g * S_ + t + 7 - D0_], 4);
      f32x4 acc = {0.f,0.f,0.f,0.f};
      if (t > 0) {
        poll_ge(&f0[g * S_ + t - 1], 4);
        stage(h0r + (size_t)((t - 1) & (D0_ - 1)) * SLOTU + goff);
        __syncthreads();
        mm3(acc);
      }
      u32* wslot = h0r + (size_t)(t & (D0_ - 1)) * SLOTU;
      #pragma unroll
      for (int j = 0; j < 4; ++j) {
        const int b = g * 16 + lhi * 4 + j;
        const float h = tanhf(acc[j] + ew[j]);
        const u16 hb = f2bf(h);
        const u16 lb = f2bf(h - bf2f(hb));
        st_sc1_u32(wslot + b * H_ + n, (u32)hb | ((u32)lb << 16));
      }
      vm0_fence();
      __syncthreads();
      if (tid == 0) post_sc1(&f0[g * S_ + t]);
    }
  } else if (role == 1) {             // ======== x1 = h0 @ Wxh1^T + bh1 ========
    const float bias = bh[H_ + n];
    for (int t = 0; t < S_; ++t) {
      if ((t & 7) == 0 && t + 7 >= DX_ && t >= 8) {
        int chk = t + 7 - DX_;
        if (chk >= 0) poll_ge(&f1[g * S_ + chk], 4);
      }
      poll_ge(&f0[g * S_ + t], 4);
      stage(h0r + (size_t)(t & (D0_ - 1)) * SLOTU + goff);
      __syncthreads();
      f32x4 acc;
      mm3(acc);
      float* xslot = x1r + (size_t)(t & (DX_ - 1)) * SLOTU;
      #pragma unroll
      for (int j = 0; j < 4; ++j) {
        const int b = g * 16 + lhi * 4 + j;
        const float v = acc[j] + bias;
        st_sc1_u32((u32*)(xslot + b * H_ + n), __builtin_bit_cast(u32, v));
      }
      vm0_fence();
      __syncthreads();
      if (tid == 0) post_sc1(&fx[g * S_ + t]);
    }
  } else {                            // ======== layer-1 recurrence ========
    for (int t = 0; t < S_; ++t) {
      poll_ge(&fx[g * S_ + t], 4);
      const float* xslot = x1r + (size_t)(t & (DX_ - 1)) * SLOTU;
      float xv[4];
      #pragma unroll
      for (int j = 0; j < 4; ++j) {
        const int b = g * 16 + lhi * 4 + j;
        xv[j] = ld_sc1_f32(xslot + b * H_ + n);
      }
      f32x4 acc = {0.f,0.f,0.f,0.f};
      if (t > 0) {
        poll_ge(&f1[g * S_ + t - 1], 4);
        stage(h1r + (size_t)((t - 1) & (D1_ - 1)) * SLOTU + goff);
        __syncthreads();
        mm3(acc);
      }
      vm0_fence();   // xv guaranteed resident (covers t==0 path too)
      u32* wslot = h1r + (size_t)(t & (D1_ - 1)) * SLOTU;
      #pragma unroll
      for (int j = 0; j < 4; ++j) {
        const int b = g * 16 + lhi * 4 + j;
        const float h = tanhf(acc[j] + xv[j]);
        const u16 hb = f2bf(h);
        const u16 lb = f2bf(h - bf2f(hb));
        st_sc1_u32(wslot + b * H_ + n, (u32)hb | ((u32)lb << 16));
        h1full[((size_t)b * S_ + t) * H_ + n] = hb;   // plain cached store
      }
      vm0_fence();
      __syncthreads();
      if (tid == 0) post_sc1(&f1[g * S_ + t]);
    }
  }
}

// ---------------------------------------------------------------------------
// out[m][o] = sum_k h1[m][k]*Why[o][k] + by[o]   (f32 out)
// ---------------------------------------------------------------------------
__global__ void k_gemm_out(const u16* __restrict__ A, const float* __restrict__ Bw,
                           const float* __restrict__ bias, float* __restrict__ outp) {
  const int tid  = threadIdx.x;
  const int wave = tid >> 6, lane = tid & 63;
  const int l15 = lane & 15, lhi = lane >> 4;
  const int m0  = blockIdx.x * 16;
  const int ncb = wave * 64;

  const u16* arow = A + ((size_t)(m0 + l15)) * H_ + lhi * 8;
  bf16x8 afr[16];
  #pragma unroll
  for (int ks = 0; ks < 16; ++ks) afr[ks] = *(const bf16x8*)(arow + ks * 32);

  f32x4 acc[4];
  #pragma unroll
  for (int nt = 0; nt < 4; ++nt) {
    const int nn = ncb + nt * 16 + l15;
    const float* wr = Bw + (size_t)nn * H_ + lhi * 8;
    f32x4 z = {0.f, 0.f, 0.f, 0.f};
    acc[nt] = z;
    #pragma unroll
    for (int ks = 0; ks < 16; ++ks) {
      const float* src = wr + ks * 32;
      bf16x8 w;
      #pragma unroll
      for (int j = 0; j < 8; ++j) w[j] = (short)f2bf(src[j]);
      acc[nt] = __builtin_amdgcn_mfma_f32_16x16x32_bf16(afr[ks], w, acc[nt], 0, 0, 0);
    }
  }
  #pragma unroll
  for (int nt = 0; nt < 4; ++nt) {
    const int nn = ncb + nt * 16 + l15;
    const float bs = bias[nn];
    #pragma unroll
    for (int j = 0; j < 4; ++j)
      outp[(size_t)(m0 + lhi * 4 + j) * O_ + nn] = acc[nt][j] + bs;
  }
}

// ---------------------------------------------------------------------------
extern "C" void kernel_launch(void* const* d_in, const int* in_sizes, int n_in,
                              void* d_out, int out_size, void* d_ws, size_t ws_size,
                              hipStream_t stream) {
  const int*   ids = (const int*)d_in[0];
  const float* emb = (const float*)d_in[1];
  const float* Wxh = (const float*)d_in[2];
  const float* Whh = (const float*)d_in[3];
  const float* bh  = (const float*)d_in[4];
  const float* Why = (const float*)d_in[5];
  const float* by  = (const float*)d_in[6];
  float* out = (float*)d_out;

  char* ws = (char*)d_ws;
  size_t off = 0;
  float* EW0  = (float*)(ws + off); off += (size_t)V_ * H_ * 4;            // 256 KB
  u32* h0r    = (u32*)(ws + off);   off += (size_t)D0_ * SLOTU * 4;        // 2 MB
  float* x1r  = (float*)(ws + off); off += (size_t)DX_ * SLOTU * 4;        // 2 MB
  u32* h1r    = (u32*)(ws + off);   off += (size_t)D1_ * SLOTU * 4;        // 512 KB
  u16* h1full = (u16*)(ws + off);   off += (size_t)B_ * S_ * H_ * 2;       // 67 MB
  u32* f0     = (u32*)(ws + off);   off += (size_t)4 * S_ * 4;             // 16 KB
  u32* fx     = (u32*)(ws + off);   off += (size_t)4 * S_ * 4;             // 16 KB
  u32* f1     = (u32*)(ws + off);   off += (size_t)4 * S_ * 4;             // 16 KB

  // flags must start at zero every call
  hipMemsetAsync(f0, 0, (size_t)3 * 4 * S_ * 4, stream);

  k_embed<<<dim3(V_), dim3(256), 0, stream>>>(emb, Wxh, bh, EW0);

  k_pipe<<<dim3(48), dim3(512), 0, stream>>>(Whh, Wxh, ids, EW0, bh,
                                             h0r, x1r, h1r, h1full, f0, fx, f1);

  k_gemm_out<<<dim3((B_ * S_) / 16), dim3(256), 0, stream>>>(h1full, Why, by, out);
}